// Round 9
// baseline (305.286 us; speedup 1.0000x reference)
//
#include <hip/hip_runtime.h>
#include <math.h>

#define B_   16
#define L_   128
#define O_   128
#define N_   256
#define S_   64
#define U_   32
#define DEL_ 64
#define HID_ 512
#define CH_  288          // N_+U_
#define M_   2048         // B_*L_
#define KD_  288          // GEMM K for the Wg projections
#define NCH8 36           // KD_/8 chunks per row
#define CM_BASE (DEL_ + N_*U_)   // 8256
#define NSLICE 32

typedef __bf16 bf16_t;
typedef bf16_t bf16x8 __attribute__((ext_vector_type(8)));
typedef float  f32x4  __attribute__((ext_vector_type(4)));

__device__ __forceinline__ float silu_f(float x){ return x / (1.f + expf(-x)); }
__device__ __forceinline__ float softplus_f(float x){
  return fmaxf(x, 0.f) + log1pf(expf(-fabsf(x)));
}

// Fragment-linear packing: element (row r, k) lives at
//   ((r>>4)*NCH8 + (k>>3))*128 + (r&15)*8 + (k&7)
// so a wave's MFMA fragment load (16 rows x 8 k, lane=lq*16+lm -> row lm+g*16,
// chunk q*4+lq) is 64 lanes x 16B contiguous.

// ---------------- prep: Wg->bf16 fragment-packed + pack x + zero loss acc ----------------
#define CVT_BLOCKS 3465   // ceil(24640*36/256)
__global__ void k_prep(const float* __restrict__ Wg, bf16_t* __restrict__ Wgp,
                       const float* __restrict__ x, float* __restrict__ Xp,
                       float* __restrict__ lossa){
  if (blockIdx.x == 0 && threadIdx.x < 2) lossa[threadIdx.x] = 0.f;
  if (blockIdx.x < CVT_BLOCKS) {
    unsigned i = blockIdx.x*256 + threadIdx.x;
    if (i >= 24640u*NCH8) return;
    unsigned r = i / NCH8, c8 = i - r*NCH8;
    const float4* src = (const float4*)(Wg + (size_t)r*KD_ + c8*8);
    float4 a = src[0], b = src[1];
    bf16x8 o;
    o[0]=(bf16_t)a.x; o[1]=(bf16_t)a.y; o[2]=(bf16_t)a.z; o[3]=(bf16_t)a.w;
    o[4]=(bf16_t)b.x; o[5]=(bf16_t)b.y; o[6]=(bf16_t)b.z; o[7]=(bf16_t)b.w;
    *(bf16x8*)(Wgp + (size_t)((r>>4)*NCH8 + c8)*128 + (r&15)*8) = o;
  } else {
    int i = (blockIdx.x - CVT_BLOCKS)*256 + threadIdx.x;
    if (i >= M_*S_) return;
    int m = i >> 6, c = i & 63;
    int b = m >> 7, t = m & 127;
    Xp[i] = x[((b<<8) + t)*S_ + c];
  }
}

// ---------------- fp32 TN GEMM (MLP) ----------------
#define GEMM_LOAD_TILES(AB, BB, KLD)                                               \
  { _Pragma("unroll")                                                              \
    for (int q = 0; q < 2; q++) {                                                  \
      int idx = tid + q*256; int row = idx >> 3; int c4 = idx & 7;                 \
      float4 av = *(const float4*)((AB) + (size_t)row*(KLD) + kk + c4*4);          \
      float4 bv = *(const float4*)((BB) + (size_t)row*(KLD) + kk + c4*4);          \
      As[c4*4+0][row]=av.x; As[c4*4+1][row]=av.y;                                  \
      As[c4*4+2][row]=av.z; As[c4*4+3][row]=av.w;                                  \
      Bs[c4*4+0][row]=bv.x; Bs[c4*4+1][row]=bv.y;                                  \
      Bs[c4*4+2][row]=bv.z; Bs[c4*4+3][row]=bv.w;                                  \
    } }

#define GEMM_MMA32()                                                               \
  { _Pragma("unroll")                                                              \
    for (int k = 0; k < 32; k++) {                                                 \
      float4 a4 = *(const float4*)&As[k][ty*4];                                    \
      float4 b4 = *(const float4*)&Bs[k][tx*4];                                    \
      float av[4] = {a4.x,a4.y,a4.z,a4.w};                                         \
      float bv[4] = {b4.x,b4.y,b4.z,b4.w};                                         \
      _Pragma("unroll") for (int i=0;i<4;i++)                                      \
        _Pragma("unroll") for (int j=0;j<4;j++)                                    \
          acc[i][j] += av[i]*bv[j];                                                \
    } }

template<int RELU>
__global__ __launch_bounds__(256) void k_gemm_tn(
    const float* __restrict__ A, const float* __restrict__ B,
    const float* __restrict__ bias, float* __restrict__ C,
    int M, int N, int K){
  __shared__ __align__(16) float As[32][68];
  __shared__ __align__(16) float Bs[32][68];
  int tid = threadIdx.x, tx = tid & 15, ty = tid >> 4;
  int nt = blockIdx.x, mt = blockIdx.y;
  const float* Ab = A + (size_t)mt*64*K;
  const float* Bb = B + (size_t)nt*64*K;
  float acc[4][4] = {};
  for (int kk = 0; kk < K; kk += 32) {
    GEMM_LOAD_TILES(Ab, Bb, K);
    __syncthreads();
    GEMM_MMA32();
    __syncthreads();
  }
  #pragma unroll
  for (int i = 0; i < 4; i++) {
    int m = mt*64 + ty*4 + i;
    float4 v; float* vv = (float*)&v;
    #pragma unroll
    for (int j = 0; j < 4; j++) {
      int n = nt*64 + tx*4 + j;
      float t = acc[i][j] + bias[n];
      vv[j] = RELU ? fmaxf(t, 0.f) : t;
    }
    *(float4*)(&C[(size_t)m*N + nt*64 + tx*4]) = v;
  }
}

// ---------------- conv (depthwise K=4) + silu -> old fp32 (row-major) + bf16 (packed) ----------------
__global__ void k_conv(const float* __restrict__ P, const float* __restrict__ u,
                       const float* __restrict__ cw, const float* __restrict__ cb,
                       float* __restrict__ oldb, bf16_t* __restrict__ oldp){
  int bl = blockIdx.x;
  int b = bl >> 7, l = bl & 127;
  int c = threadIdx.x;
  if (c >= CH_) return;
  float acc = cb[c];
  #pragma unroll
  for (int k = 0; k < 4; k++) {
    int t = l + k - 1;
    if (t >= 0 && t <= O_-2) {
      float s;
      if (c < N_) s = P[((b<<7) + t)*N_ + c];
      else        s = u[((b<<8) + t)*U_ + (c - N_)];
      acc += silu_f(s) * cw[c*4 + k];
    }
  }
  float v = silu_f(acc);
  oldb[(size_t)bl*CH_ + c] = v;
  oldp[(size_t)((bl>>4)*NCH8 + (c>>3))*128 + ((bl&15)<<3) + (c&7)] = (bf16_t)v;
}

// ---------------- delta path with fused draw GEMM ----------------
__global__ __launch_bounds__(256) void k_delta(
    const float* __restrict__ oldb, const float* __restrict__ Wg,
    const float* __restrict__ bg, const float* __restrict__ Wdt,
    const float* __restrict__ bdt, const float* __restrict__ Ap,
    float* __restrict__ dA, float* __restrict__ coef){
  __shared__ __align__(16) float olds[16*KD_];
  __shared__ float dr[16][64];
  int tid = threadIdx.x;
  int m0 = blockIdx.x * 16;
  {
    const float4* src = (const float4*)(oldb + (size_t)m0*KD_);
    float4* dst = (float4*)olds;
    #pragma unroll
    for (int q = 0; q < 5; q++) {
      int i = tid + q*256;
      if (i < 16*KD_/4) dst[i] = src[i];
    }
  }
  __syncthreads();
  {
    int d = tid & 63;
    int r0 = (tid >> 6) * 4;
    const float* wrow = Wg + (size_t)d*KD_;
    float s0=0.f,s1=0.f,s2=0.f,s3=0.f;
    for (int k = 0; k < KD_; k++) {
      float wv = wrow[k];
      s0 += olds[(r0+0)*KD_+k]*wv;
      s1 += olds[(r0+1)*KD_+k]*wv;
      s2 += olds[(r0+2)*KD_+k]*wv;
      s3 += olds[(r0+3)*KD_+k]*wv;
    }
    float bgd = bg[d];
    dr[r0+0][d] = s0 + bgd;
    dr[r0+1][d] = s1 + bgd;
    dr[r0+2][d] = s2 + bgd;
    dr[r0+3][d] = s3 + bgd;
  }
  __syncthreads();
  int n = tid;
  float wrow[64];
  #pragma unroll
  for (int d = 0; d < 64; d++) wrow[d] = Wdt[n*64 + d];
  float a0 = Ap[n];
  float a = -(a0 > 0.f ? a0 : expm1f(a0));
  float inva = 1.f / a;
  float bd = bdt[n];
  for (int r = 0; r < 16; r++) {
    float s = bd;
    #pragma unroll
    for (int d = 0; d < 64; d++) s += dr[r][d] * wrow[d];
    float dd = softplus_f(s);
    float e  = expf(dd * a);
    size_t m = m0 + r;
    dA[m*N_ + n]   = e;
    coef[m*N_ + n] = (e - 1.f) * inva;
  }
}

// Direct fragment load from packed array: row-group rg, chunk-quad q.
// laneoff = lq*128 + lm*8 (elems); 64 lanes read 1024 contiguous bytes.
#define FRAG(PK, RG, Q) (*(const bf16x8*)&(PK)[(size_t)((RG)*NCH8 + (Q)*4)*128 + laneoff])

// ---------------- B-path MFMA: barrier-free direct-load K-loop ----------------
__global__ __launch_bounds__(256, 2) void k_bmfma(
    const bf16_t* __restrict__ oldp, const bf16_t* __restrict__ Wgp,
    const float* __restrict__ bg, const float* __restrict__ u,
    const float* __restrict__ coef, float* __restrict__ wbuf){
  int tid = threadIdx.x;
  int wave = tid >> 6, lane = tid & 63;
  int wm = wave & 1, wn = wave >> 1;
  int mt = blockIdx.y, nt = blockIdx.x;
  int m0 = mt*128, ncol0 = nt*128;
  int lm = lane & 15, lq = lane >> 4;
  int laneoff = lq*128 + lm*8;
  int arg0 = mt*8 + wm*4;                        // A row-group base
  int brg0 = (DEL_ + ncol0 >> 4) + wn*4;         // B row-group base (64/16=4 + nt*8)

  f32x4 acc[4][4];
  #pragma unroll
  for (int i=0;i<4;i++)
    #pragma unroll
    for (int j=0;j<4;j++){ acc[i][j][0]=0.f;acc[i][j][1]=0.f;acc[i][j][2]=0.f;acc[i][j][3]=0.f; }

  #pragma unroll
  for (int q = 0; q < 9; q++) {
    bf16x8 af[4], bff[4];
    #pragma unroll
    for (int i=0;i<4;i++) af[i]  = FRAG(oldp, arg0 + i, q);
    #pragma unroll
    for (int j=0;j<4;j++) bff[j] = FRAG(Wgp, brg0 + j, q);
    #pragma unroll
    for (int i=0;i<4;i++)
      #pragma unroll
      for (int j=0;j<4;j++)
        acc[i][j] = __builtin_amdgcn_mfma_f32_16x16x32_bf16(af[i], bff[j], acc[i][j], 0,0,0);
  }

  float bgv[4];
  #pragma unroll
  for (int j=0;j<4;j++) bgv[j] = bg[DEL_ + ncol0 + wn*64 + j*16 + lm];
  float p[2][4][4];
  #pragma unroll
  for (int a=0;a<2;a++)
    #pragma unroll
    for (int i=0;i<4;i++)
      #pragma unroll
      for (int r=0;r<4;r++) p[a][i][r]=0.f;
  #pragma unroll
  for (int i=0;i<4;i++){
    #pragma unroll
    for (int r=0;r<4;r++){
      int m = m0 + wm*64 + i*16 + lq*4 + r;
      int b = m >> 7, l = m & 127;
      const float* urow = u + ((size_t)(b<<8) + 127 + l)*U_;
      #pragma unroll
      for (int j=0;j<4;j++){
        float uu = urow[(j&1)*16 + lm];
        p[j>>1][i][r] += (acc[i][j][r] + bgv[j]) * uu;
      }
    }
  }
  #pragma unroll
  for (int mk = 1; mk < 16; mk <<= 1){
    #pragma unroll
    for (int a=0;a<2;a++)
      #pragma unroll
      for (int i=0;i<4;i++)
        #pragma unroll
        for (int r=0;r<4;r++) p[a][i][r] += __shfl_xor(p[a][i][r], mk);
  }
  if (lm == 0){
    #pragma unroll
    for (int nl=0;nl<2;nl++){
      int n = ((ncol0 + wn*64 + nl*32) >> 5);
      #pragma unroll
      for (int i=0;i<4;i++)
        #pragma unroll
        for (int r=0;r<4;r++){
          int m = m0 + wm*64 + i*16 + lq*4 + r;
          wbuf[(size_t)m*N_ + n] = coef[(size_t)m*N_ + n] * p[nl][i][r];
        }
    }
  }
}

// ---------------- sequential scan (batched loads) ----------------
__global__ void k_scan(const float* __restrict__ P, const float* __restrict__ dA,
                       const float* __restrict__ w, float* __restrict__ zall){
  int blk = blockIdx.x;             // 64
  int b = blk >> 2;
  int n = (blk & 3)*64 + threadIdx.x;
  float z = P[(size_t)((b<<7) + 127)*N_ + n];
  for (int l0 = 0; l0 < L_; l0 += 16) {
    float da[16], ww[16];
    #pragma unroll
    for (int t = 0; t < 16; t++) {
      size_t idx = (size_t)((b<<7) + l0 + t)*N_ + n;
      da[t] = dA[idx]; ww[t] = w[idx];
    }
    #pragma unroll
    for (int t = 0; t < 16; t++) {
      size_t idx = (size_t)((b<<7) + l0 + t)*N_ + n;
      z = z * da[t] + ww[t];
      zall[idx] = z;
    }
  }
}

// ---------------- C-path MFMA: barrier-free direct-load, 4 n-tiles/block ----------------
__global__ __launch_bounds__(256, 2) void k_cmfma(
    const bf16_t* __restrict__ oldp, const bf16_t* __restrict__ Wgp,
    const float* __restrict__ bg, const float* __restrict__ zall,
    float* __restrict__ ypart){
  __shared__ float ylds[128][64];
  int tid = threadIdx.x;
  int wave = tid >> 6, lane = tid & 63;
  int wm = wave & 1, wn = wave >> 1;
  int mt = blockIdx.y, grp = blockIdx.x;   // 32 groups of 4 n-tiles
  int m0 = mt*128;
  int lm = lane & 15, lq = lane >> 4;
  int laneoff = lq*128 + lm*8;
  int arg0 = mt*8 + wm*4;

  f32x4 yacc[4][4];
  #pragma unroll
  for (int i=0;i<4;i++)
    #pragma unroll
    for (int j=0;j<4;j++){ yacc[i][j][0]=0.f;yacc[i][j][1]=0.f;yacc[i][j][2]=0.f;yacc[i][j][3]=0.f; }

  for (int it = 0; it < 4; it++) {
    int ncol0 = (grp*4 + it)*128;
    int brg0 = (CM_BASE >> 4) + (ncol0 >> 4) + wn*4;   // 516 + ...
    f32x4 acc[4][4];
    #pragma unroll
    for (int i=0;i<4;i++)
      #pragma unroll
      for (int j=0;j<4;j++){ acc[i][j][0]=0.f;acc[i][j][1]=0.f;acc[i][j][2]=0.f;acc[i][j][3]=0.f; }

    #pragma unroll
    for (int q = 0; q < 9; q++) {
      bf16x8 af[4], bff[4];
      #pragma unroll
      for (int i=0;i<4;i++) af[i]  = FRAG(oldp, arg0 + i, q);
      #pragma unroll
      for (int j=0;j<4;j++) bff[j] = FRAG(Wgp, brg0 + j, q);
      #pragma unroll
      for (int i=0;i<4;i++)
        #pragma unroll
        for (int j=0;j<4;j++)
          acc[i][j] = __builtin_amdgcn_mfma_f32_16x16x32_bf16(af[i], bff[j], acc[i][j], 0,0,0);
    }

    int n = (ncol0 >> 6) + wn;
    float bgv[4];
    #pragma unroll
    for (int j=0;j<4;j++) bgv[j] = bg[CM_BASE + ncol0 + wn*64 + j*16 + lm];
    #pragma unroll
    for (int i=0;i<4;i++){
      #pragma unroll
      for (int r=0;r<4;r++){
        int m = m0 + wm*64 + i*16 + lq*4 + r;
        float zv = zall[(size_t)m*N_ + n];
        #pragma unroll
        for (int j=0;j<4;j++)
          yacc[i][j][r] += (acc[i][j][r] + bgv[j]) * zv;
      }
    }
  }

  __syncthreads();
  if (wn == 1){
    #pragma unroll
    for (int i=0;i<4;i++)
      #pragma unroll
      for (int j=0;j<4;j++)
        #pragma unroll
        for (int r=0;r<4;r++){
          int ml = wm*64 + i*16 + lq*4 + r;
          ylds[ml][j*16 + lm] = yacc[i][j][r];
        }
  }
  __syncthreads();
  if (wn == 0){
    float* dst = ypart + (size_t)grp*(M_*S_);
    #pragma unroll
    for (int i=0;i<4;i++)
      #pragma unroll
      for (int j=0;j<4;j++)
        #pragma unroll
        for (int r=0;r<4;r++){
          int ml = wm*64 + i*16 + lq*4 + r;
          int s = j*16 + lm;
          dst[(size_t)(m0+ml)*S_ + s] = yacc[i][j][r] + ylds[ml][s];
        }
  }
}

// ---------------- finalize: sum slices, write ys (L,B,S), fused loss ----------------
__global__ void k_finalize(const float* __restrict__ ypart, const float* __restrict__ x,
                           float* __restrict__ out, float* __restrict__ lossacc){
  __shared__ float red[256];
  int tid = threadIdx.x;
  float ls = 0.f;
  #pragma unroll
  for (int q = 0; q < 2; q++) {
    int e = blockIdx.x*512 + q*256 + tid;
    int m = e >> 6, s = e & 63;
    int b = m >> 7, l = m & 127;
    float yv = 0.f;
    #pragma unroll 8
    for (int g = 0; g < NSLICE; g++) yv += ypart[(size_t)g*(M_*S_) + e];
    out[1 + (size_t)((l<<4) + b)*S_ + s] = yv;
    float xv = x[((size_t)(b<<8) + 128 + l)*S_ + s];
    float d = yv - xv;
    ls += d*d;
  }
  red[tid] = ls; __syncthreads();
  for (int st = 128; st > 0; st >>= 1) {
    if (tid < st) red[tid] += red[tid+st];
    __syncthreads();
  }
  if (tid == 0) {
    atomicAdd(&lossacc[0], red[0]);
    __threadfence();
    unsigned old = atomicAdd((unsigned*)&lossacc[1], 1u);
    if (old == 255u) {
      float tot = atomicAdd(&lossacc[0], 0.f);   // atomic read (bypass L1)
      out[0] = tot * (1.f / (float)(B_*S_*L_));
    }
  }
}

extern "C" void kernel_launch(void* const* d_in, const int* in_sizes, int n_in,
                              void* d_out, int out_size, void* d_ws, size_t ws_size,
                              hipStream_t stream) {
  const float* x   = (const float*)d_in[0];
  const float* u   = (const float*)d_in[1];
  const float* Ap  = (const float*)d_in[2];
  const float* W0  = (const float*)d_in[3];
  const float* b0  = (const float*)d_in[4];
  const float* W1  = (const float*)d_in[5];
  const float* b1  = (const float*)d_in[6];
  const float* cw  = (const float*)d_in[7];
  const float* cb  = (const float*)d_in[8];
  const float* Wg  = (const float*)d_in[9];
  const float* bg  = (const float*)d_in[10];
  const float* Wdt = (const float*)d_in[11];
  const float* bdt = (const float*)d_in[12];
  float* out = (float*)d_out;

  // Layout: persistent buffers first; region R of fp32 temps (dead before
  // k_cmfma) is overlaid by ypart (32 slices = 16 MB).
  float* ws    = (float*)d_ws;
  float* zall  = ws;                       // 524288
  float* lossa = zall + 524288;            // 512 (acc, counter)
  bf16_t* oldp = (bf16_t*)(lossa + 512);   // 294912 f32 slots (packed)
  bf16_t* Wgp  = (bf16_t*)(lossa + 512 + 294912);  // 3548160 f32 slots (packed)
  float* R     = lossa + 512 + 294912 + 3548160;
  float* Xp    = R;                        // 131072
  float* Hh    = Xp   + 131072;            // 1048576
  float* Pp    = Hh   + 1048576;           // 524288
  float* oldb  = Pp   + 524288;            // 589824
  float* dA    = oldb + 589824;            // 524288
  float* coef  = dA   + 524288;            // 524288
  float* wbuf  = coef + 524288;            // 524288
  float* ypart = R;                        // 32*131072 = 4194304, overlays R

  k_prep<<<CVT_BLOCKS + 512, 256, 0, stream>>>(Wg, Wgp, x, Xp, lossa);
  k_gemm_tn<1><<<dim3(HID_/64, M_/64), 256, 0, stream>>>(Xp, W0, b0, Hh, M_, HID_, S_);
  k_gemm_tn<0><<<dim3(N_/64, M_/64), 256, 0, stream>>>(Hh, W1, b1, Pp, M_, N_, HID_);
  k_conv<<<M_, 320, 0, stream>>>(Pp, u, cw, cb, oldb, oldp);
  k_delta<<<M_/16, 256, 0, stream>>>(oldb, Wg, bg, Wdt, bdt, Ap, dA, coef);
  k_bmfma<<<dim3(64, 16), 256, 0, stream>>>(oldp, Wgp, bg, u, coef, wbuf);
  k_scan<<<64, 64, 0, stream>>>(Pp, dA, wbuf, zall);
  k_cmfma<<<dim3(32, 16), 256, 0, stream>>>(oldp, Wgp, bg, zall, ypart);
  k_finalize<<<256, 256, 0, stream>>>(ypart, x, out, lossa);
}

// Round 10
// 262.200 us; speedup vs baseline: 1.1643x; 1.1643x over previous
//
#include <hip/hip_runtime.h>
#include <math.h>

#define B_   16
#define L_   128
#define O_   128
#define N_   256
#define S_   64
#define U_   32
#define DEL_ 64
#define HID_ 512
#define CH_  288          // N_+U_
#define M_   2048         // B_*L_
#define KD_  288          // GEMM K for the Wg projections
#define CM_BASE (DEL_ + N_*U_)   // 8256
#define NSLICE 32

typedef __bf16 bf16_t;
typedef bf16_t bf16x8 __attribute__((ext_vector_type(8)));
typedef float  f32x4  __attribute__((ext_vector_type(4)));

#define AS1(p) ((const __attribute__((address_space(1))) void*)(unsigned long long)(const void*)(p))
#define AS3(p) ((__attribute__((address_space(3))) void*)(unsigned int)(unsigned long long)(const void*)(p))

__device__ __forceinline__ float silu_f(float x){ return x / (1.f + expf(-x)); }
__device__ __forceinline__ float softplus_f(float x){
  return fmaxf(x, 0.f) + log1pf(expf(-fabsf(x)));
}

// ---------------- prep: Wg->bf16 convert + pack x + zero loss acc ----------------
#define CVT_BLOCKS 3465   // ceil(887040/256)
__global__ void k_prep(const float* __restrict__ Wg, bf16_t* __restrict__ Wgbf,
                       const float* __restrict__ x, float* __restrict__ Xp,
                       float* __restrict__ lossa){
  if (blockIdx.x == 0 && threadIdx.x < 2) lossa[threadIdx.x] = 0.f;
  if (blockIdx.x < CVT_BLOCKS) {
    int i = blockIdx.x*256 + threadIdx.x;
    if (i >= 887040) return;          // 7096320/8
    float4 a = ((const float4*)Wg)[2*i];
    float4 b = ((const float4*)Wg)[2*i+1];
    bf16x8 o;
    o[0]=(bf16_t)a.x; o[1]=(bf16_t)a.y; o[2]=(bf16_t)a.z; o[3]=(bf16_t)a.w;
    o[4]=(bf16_t)b.x; o[5]=(bf16_t)b.y; o[6]=(bf16_t)b.z; o[7]=(bf16_t)b.w;
    ((bf16x8*)Wgbf)[i] = o;
  } else {
    int i = (blockIdx.x - CVT_BLOCKS)*256 + threadIdx.x;
    if (i >= M_*S_) return;
    int m = i >> 6, c = i & 63;
    int b = m >> 7, t = m & 127;
    Xp[i] = x[((b<<8) + t)*S_ + c];
  }
}

// ---------------- fp32 TN GEMM, 64x64 tile (mlp1) ----------------
#define GEMM_LOAD_TILES(AB, BB, KLD)                                               \
  { _Pragma("unroll")                                                              \
    for (int q = 0; q < 2; q++) {                                                  \
      int idx = tid + q*256; int row = idx >> 3; int c4 = idx & 7;                 \
      float4 av = *(const float4*)((AB) + (size_t)row*(KLD) + kk + c4*4);          \
      float4 bv = *(const float4*)((BB) + (size_t)row*(KLD) + kk + c4*4);          \
      As[c4*4+0][row]=av.x; As[c4*4+1][row]=av.y;                                  \
      As[c4*4+2][row]=av.z; As[c4*4+3][row]=av.w;                                  \
      Bs[c4*4+0][row]=bv.x; Bs[c4*4+1][row]=bv.y;                                  \
      Bs[c4*4+2][row]=bv.z; Bs[c4*4+3][row]=bv.w;                                  \
    } }

#define GEMM_MMA32()                                                               \
  { _Pragma("unroll")                                                              \
    for (int k = 0; k < 32; k++) {                                                 \
      float4 a4 = *(const float4*)&As[k][ty*4];                                    \
      float4 b4 = *(const float4*)&Bs[k][tx*4];                                    \
      float av[4] = {a4.x,a4.y,a4.z,a4.w};                                         \
      float bv[4] = {b4.x,b4.y,b4.z,b4.w};                                         \
      _Pragma("unroll") for (int i=0;i<4;i++)                                      \
        _Pragma("unroll") for (int j=0;j<4;j++)                                    \
          acc[i][j] += av[i]*bv[j];                                                \
    } }

template<int RELU>
__global__ __launch_bounds__(256) void k_gemm_tn(
    const float* __restrict__ A, const float* __restrict__ B,
    const float* __restrict__ bias, float* __restrict__ C,
    int M, int N, int K){
  __shared__ __align__(16) float As[32][68];
  __shared__ __align__(16) float Bs[32][68];
  int tid = threadIdx.x, tx = tid & 15, ty = tid >> 4;
  int nt = blockIdx.x, mt = blockIdx.y;
  const float* Ab = A + (size_t)mt*64*K;
  const float* Bb = B + (size_t)nt*64*K;
  float acc[4][4] = {};
  for (int kk = 0; kk < K; kk += 32) {
    GEMM_LOAD_TILES(Ab, Bb, K);
    __syncthreads();
    GEMM_MMA32();
    __syncthreads();
  }
  #pragma unroll
  for (int i = 0; i < 4; i++) {
    int m = mt*64 + ty*4 + i;
    float4 v; float* vv = (float*)&v;
    #pragma unroll
    for (int j = 0; j < 4; j++) {
      int n = nt*64 + tx*4 + j;
      float t = acc[i][j] + bias[n];
      vv[j] = RELU ? fmaxf(t, 0.f) : t;
    }
    *(float4*)(&C[(size_t)m*N + nt*64 + tx*4]) = v;
  }
}

// ---------------- fp32 TN GEMM, 32x64 tile (mlp2: doubles grid to 256 blocks) ----------------
__global__ __launch_bounds__(256) void k_gemm_tn_s(
    const float* __restrict__ A, const float* __restrict__ B,
    const float* __restrict__ bias, float* __restrict__ C,
    int M, int N, int K){
  __shared__ __align__(16) float As[32][36];
  __shared__ __align__(16) float Bs[32][68];
  int tid = threadIdx.x, tx = tid & 15, ty = tid >> 4;
  int nt = blockIdx.x, mt = blockIdx.y;
  const float* Ab = A + (size_t)mt*32*K;
  const float* Bb = B + (size_t)nt*64*K;
  float acc[2][4] = {};
  for (int kk = 0; kk < K; kk += 32) {
    { int row = tid >> 3, c4 = tid & 7;
      float4 av = *(const float4*)(Ab + (size_t)row*K + kk + c4*4);
      As[c4*4+0][row]=av.x; As[c4*4+1][row]=av.y;
      As[c4*4+2][row]=av.z; As[c4*4+3][row]=av.w; }
    #pragma unroll
    for (int q = 0; q < 2; q++) {
      int idx = tid + q*256; int row = idx >> 3; int c4 = idx & 7;
      float4 bv = *(const float4*)(Bb + (size_t)row*K + kk + c4*4);
      Bs[c4*4+0][row]=bv.x; Bs[c4*4+1][row]=bv.y;
      Bs[c4*4+2][row]=bv.z; Bs[c4*4+3][row]=bv.w; }
    __syncthreads();
    #pragma unroll
    for (int k = 0; k < 32; k++) {
      float a0 = As[k][ty*2], a1 = As[k][ty*2+1];
      float4 b4 = *(const float4*)&Bs[k][tx*4];
      float bv[4] = {b4.x,b4.y,b4.z,b4.w};
      #pragma unroll
      for (int j=0;j<4;j++){ acc[0][j] += a0*bv[j]; acc[1][j] += a1*bv[j]; }
    }
    __syncthreads();
  }
  #pragma unroll
  for (int i = 0; i < 2; i++) {
    int m = mt*32 + ty*2 + i;
    float4 v; float* vv = (float*)&v;
    #pragma unroll
    for (int j = 0; j < 4; j++) vv[j] = acc[i][j] + bias[nt*64 + tx*4 + j];
    *(float4*)(&C[(size_t)m*N + nt*64 + tx*4]) = v;
  }
}

// ---------------- fused conv + delta: computes old in-LDS, writes bf16 old + dA/coef ----------------
__global__ __launch_bounds__(256) void k_convdelta(
    const float* __restrict__ P, const float* __restrict__ u,
    const float* __restrict__ cw, const float* __restrict__ cb,
    const float* __restrict__ Wg, const float* __restrict__ bg,
    const float* __restrict__ Wdt, const float* __restrict__ bdt,
    const float* __restrict__ Ap, bf16_t* __restrict__ oldbf,
    float* __restrict__ dA, float* __restrict__ coef){
  __shared__ __align__(16) float olds[16*KD_];
  __shared__ float dr[16][64];
  int tid = threadIdx.x;
  int m0 = blockIdx.x * 16;
  int b = m0 >> 7, l0 = m0 & 127;
  // conv phase: 16 rows x 288 ch
  for (int e = tid; e < 16*CH_; e += 256) {
    int r = e / CH_, c = e - r*CH_;
    int l = l0 + r;
    float acc = cb[c];
    #pragma unroll
    for (int k = 0; k < 4; k++) {
      int t = l + k - 1;
      if (t >= 0 && t <= O_-2) {
        float s = (c < N_) ? P[((b<<7)+t)*N_ + c] : u[((b<<8)+t)*U_ + (c-N_)];
        acc += silu_f(s) * cw[c*4 + k];
      }
    }
    float v = silu_f(acc);
    olds[e] = v;
    oldbf[(size_t)(m0+r)*CH_ + c] = (bf16_t)v;
  }
  __syncthreads();
  // draw phase
  {
    int d = tid & 63;
    int r0 = (tid >> 6) * 4;
    const float* wrow = Wg + (size_t)d*KD_;
    float s0=0.f,s1=0.f,s2=0.f,s3=0.f;
    for (int k = 0; k < KD_; k++) {
      float wv = wrow[k];
      s0 += olds[(r0+0)*KD_+k]*wv;
      s1 += olds[(r0+1)*KD_+k]*wv;
      s2 += olds[(r0+2)*KD_+k]*wv;
      s3 += olds[(r0+3)*KD_+k]*wv;
    }
    float bgd = bg[d];
    dr[r0+0][d] = s0 + bgd;
    dr[r0+1][d] = s1 + bgd;
    dr[r0+2][d] = s2 + bgd;
    dr[r0+3][d] = s3 + bgd;
  }
  __syncthreads();
  // delta phase
  int n = tid;
  float wrow[64];
  #pragma unroll
  for (int d = 0; d < 64; d++) wrow[d] = Wdt[n*64 + d];
  float a0 = Ap[n];
  float a = -(a0 > 0.f ? a0 : expm1f(a0));
  float inva = 1.f / a;
  float bd = bdt[n];
  for (int r = 0; r < 16; r++) {
    float s = bd;
    #pragma unroll
    for (int d = 0; d < 64; d++) s += dr[r][d] * wrow[d];
    float dd = softplus_f(s);
    float e  = expf(dd * a);
    size_t m = m0 + r;
    dA[m*N_ + n]   = e;
    coef[m*N_ + n] = (e - 1.f) * inva;
  }
}

// ================= fragment-order staging, BK=96 (3 col-blocks of 32) =================
#define STAGE_FR96(GBASE, ROW0G, LDSARR)                                                 \
  { _Pragma("unroll")                                                                    \
    for (int c = 0; c < 3; c++) {                                                        \
      _Pragma("unroll")                                                                  \
      for (int q = 0; q < 2; q++) {                                                      \
        int g = wave*2 + q;                                                              \
        const bf16_t* gp = (GBASE) + (size_t)((ROW0G) + g*16 + lm)*KD_ + kk + c*32 + lq*8;\
        __builtin_amdgcn_global_load_lds(AS1(gp), AS3(&(LDSARR)[c*4096 + g*512]), 16, 0, 0);\
      } } }

// ---------------- B-path MFMA (BK=96) ----------------
__global__ __launch_bounds__(256, 2) void k_bmfma(
    const bf16_t* __restrict__ oldbf, const bf16_t* __restrict__ Wgbf,
    const float* __restrict__ bg, const float* __restrict__ u,
    const float* __restrict__ coef, float* __restrict__ wbuf){
  __shared__ __align__(16) bf16_t Asb[3*4096];
  __shared__ __align__(16) bf16_t Bsb[3*4096];
  int tid = threadIdx.x;
  int wave = tid >> 6, lane = tid & 63;
  int wm = wave & 1, wn = wave >> 1;
  int mt = blockIdx.y, nt = blockIdx.x;
  int m0 = mt*128, ncol0 = nt*128;
  int lm = lane & 15, lq = lane >> 4;

  f32x4 acc[4][4];
  #pragma unroll
  for (int i=0;i<4;i++)
    #pragma unroll
    for (int j=0;j<4;j++){ acc[i][j][0]=0.f;acc[i][j][1]=0.f;acc[i][j][2]=0.f;acc[i][j][3]=0.f; }

  for (int kk = 0; kk < KD_; kk += 96) {
    STAGE_FR96(oldbf, m0, Asb);
    STAGE_FR96(Wgbf, DEL_ + ncol0, Bsb);
    __syncthreads();
    for (int c = 0; c < 3; c++) {
      bf16x8 af[4], bff[4];
      #pragma unroll
      for (int i=0;i<4;i++) af[i]  = *(const bf16x8*)&Asb[c*4096 + (wm*4 + i)*512 + lane*8];
      #pragma unroll
      for (int j=0;j<4;j++) bff[j] = *(const bf16x8*)&Bsb[c*4096 + (wn*4 + j)*512 + lane*8];
      #pragma unroll
      for (int i=0;i<4;i++)
        #pragma unroll
        for (int j=0;j<4;j++)
          acc[i][j] = __builtin_amdgcn_mfma_f32_16x16x32_bf16(af[i], bff[j], acc[i][j], 0,0,0);
    }
    __syncthreads();
  }

  float bgv[4];
  #pragma unroll
  for (int j=0;j<4;j++) bgv[j] = bg[DEL_ + ncol0 + wn*64 + j*16 + lm];
  float p[2][4][4];
  #pragma unroll
  for (int a=0;a<2;a++)
    #pragma unroll
    for (int i=0;i<4;i++)
      #pragma unroll
      for (int r=0;r<4;r++) p[a][i][r]=0.f;
  #pragma unroll
  for (int i=0;i<4;i++){
    #pragma unroll
    for (int r=0;r<4;r++){
      int m = m0 + wm*64 + i*16 + lq*4 + r;
      int b = m >> 7, l = m & 127;
      const float* urow = u + ((size_t)(b<<8) + 127 + l)*U_;
      #pragma unroll
      for (int j=0;j<4;j++){
        float uu = urow[(j&1)*16 + lm];
        p[j>>1][i][r] += (acc[i][j][r] + bgv[j]) * uu;
      }
    }
  }
  #pragma unroll
  for (int mk = 1; mk < 16; mk <<= 1){
    #pragma unroll
    for (int a=0;a<2;a++)
      #pragma unroll
      for (int i=0;i<4;i++)
        #pragma unroll
        for (int r=0;r<4;r++) p[a][i][r] += __shfl_xor(p[a][i][r], mk);
  }
  if (lm == 0){
    #pragma unroll
    for (int nl=0;nl<2;nl++){
      int n = ((ncol0 + wn*64 + nl*32) >> 5);
      #pragma unroll
      for (int i=0;i<4;i++)
        #pragma unroll
        for (int r=0;r<4;r++){
          int m = m0 + wm*64 + i*16 + lq*4 + r;
          wbuf[(size_t)m*N_ + n] = coef[(size_t)m*N_ + n] * p[nl][i][r];
        }
    }
  }
}

// ---------------- sequential scan (batched loads) ----------------
__global__ void k_scan(const float* __restrict__ P, const float* __restrict__ dA,
                       const float* __restrict__ w, float* __restrict__ zall){
  int blk = blockIdx.x;             // 64
  int b = blk >> 2;
  int n = (blk & 3)*64 + threadIdx.x;
  float z = P[(size_t)((b<<7) + 127)*N_ + n];
  for (int l0 = 0; l0 < L_; l0 += 16) {
    float da[16], ww[16];
    #pragma unroll
    for (int t = 0; t < 16; t++) {
      size_t idx = (size_t)((b<<7) + l0 + t)*N_ + n;
      da[t] = dA[idx]; ww[t] = w[idx];
    }
    #pragma unroll
    for (int t = 0; t < 16; t++) {
      size_t idx = (size_t)((b<<7) + l0 + t)*N_ + n;
      z = z * da[t] + ww[t];
      zall[idx] = z;
    }
  }
}

// ---------------- C-path MFMA (BK=96): 4 n-tiles/block, per-block y slice ----------------
__global__ __launch_bounds__(256, 2) void k_cmfma(
    const bf16_t* __restrict__ oldbf, const bf16_t* __restrict__ Wgbf,
    const float* __restrict__ bg, const float* __restrict__ zall,
    float* __restrict__ ypart){
  __shared__ union {
    struct { bf16_t A[3*4096]; bf16_t B[3*4096]; } st;   // 48 KB staging
    float ylds[128][64];                                  // 32 KB (after staging dead)
  } sm;
  int tid = threadIdx.x;
  int wave = tid >> 6, lane = tid & 63;
  int wm = wave & 1, wn = wave >> 1;
  int mt = blockIdx.y, grp = blockIdx.x;   // 32 groups of 4 n-tiles
  int m0 = mt*128;
  int lm = lane & 15, lq = lane >> 4;

  f32x4 yacc[4][4];
  #pragma unroll
  for (int i=0;i<4;i++)
    #pragma unroll
    for (int j=0;j<4;j++){ yacc[i][j][0]=0.f;yacc[i][j][1]=0.f;yacc[i][j][2]=0.f;yacc[i][j][3]=0.f; }

  for (int it = 0; it < 4; it++) {
    int ncol0 = (grp*4 + it)*128;
    f32x4 acc[4][4];
    #pragma unroll
    for (int i=0;i<4;i++)
      #pragma unroll
      for (int j=0;j<4;j++){ acc[i][j][0]=0.f;acc[i][j][1]=0.f;acc[i][j][2]=0.f;acc[i][j][3]=0.f; }

    for (int kk = 0; kk < KD_; kk += 96) {
      STAGE_FR96(oldbf, m0, sm.st.A);
      STAGE_FR96(Wgbf, CM_BASE + ncol0, sm.st.B);
      __syncthreads();
      for (int c = 0; c < 3; c++) {
        bf16x8 af[4], bff[4];
        #pragma unroll
        for (int i=0;i<4;i++) af[i]  = *(const bf16x8*)&sm.st.A[c*4096 + (wm*4 + i)*512 + lane*8];
        #pragma unroll
        for (int j=0;j<4;j++) bff[j] = *(const bf16x8*)&sm.st.B[c*4096 + (wn*4 + j)*512 + lane*8];
        #pragma unroll
        for (int i=0;i<4;i++)
          #pragma unroll
          for (int j=0;j<4;j++)
            acc[i][j] = __builtin_amdgcn_mfma_f32_16x16x32_bf16(af[i], bff[j], acc[i][j], 0,0,0);
      }
      __syncthreads();
    }

    int n = (ncol0 >> 6) + wn;
    float bgv[4];
    #pragma unroll
    for (int j=0;j<4;j++) bgv[j] = bg[CM_BASE + ncol0 + wn*64 + j*16 + lm];
    #pragma unroll
    for (int i=0;i<4;i++){
      #pragma unroll
      for (int r=0;r<4;r++){
        int m = m0 + wm*64 + i*16 + lq*4 + r;
        float zv = zall[(size_t)m*N_ + n];
        #pragma unroll
        for (int j=0;j<4;j++)
          yacc[i][j][r] += (acc[i][j][r] + bgv[j]) * zv;
      }
    }
  }

  __syncthreads();
  if (wn == 1){
    #pragma unroll
    for (int i=0;i<4;i++)
      #pragma unroll
      for (int j=0;j<4;j++)
        #pragma unroll
        for (int r=0;r<4;r++){
          int ml = wm*64 + i*16 + lq*4 + r;
          sm.ylds[ml][j*16 + lm] = yacc[i][j][r];
        }
  }
  __syncthreads();
  if (wn == 0){
    float* dst = ypart + (size_t)grp*(M_*S_);
    #pragma unroll
    for (int i=0;i<4;i++)
      #pragma unroll
      for (int j=0;j<4;j++)
        #pragma unroll
        for (int r=0;r<4;r++){
          int ml = wm*64 + i*16 + lq*4 + r;
          int s = j*16 + lm;
          dst[(size_t)(m0+ml)*S_ + s] = yacc[i][j][r] + sm.ylds[ml][s];
        }
  }
}

// ---------------- finalize: sum slices, write ys (L,B,S), fused loss ----------------
__global__ void k_finalize(const float* __restrict__ ypart, const float* __restrict__ x,
                           float* __restrict__ out, float* __restrict__ lossacc){
  __shared__ float red[256];
  int tid = threadIdx.x;
  float ls = 0.f;
  #pragma unroll
  for (int q = 0; q < 2; q++) {
    int e = blockIdx.x*512 + q*256 + tid;
    int m = e >> 6, s = e & 63;
    int b = m >> 7, l = m & 127;
    float yv = 0.f;
    #pragma unroll 8
    for (int g = 0; g < NSLICE; g++) yv += ypart[(size_t)g*(M_*S_) + e];
    out[1 + (size_t)((l<<4) + b)*S_ + s] = yv;
    float xv = x[((size_t)(b<<8) + 128 + l)*S_ + s];
    float d = yv - xv;
    ls += d*d;
  }
  red[tid] = ls; __syncthreads();
  for (int st = 128; st > 0; st >>= 1) {
    if (tid < st) red[tid] += red[tid+st];
    __syncthreads();
  }
  if (tid == 0) {
    atomicAdd(&lossacc[0], red[0]);
    __threadfence();
    unsigned old = atomicAdd((unsigned*)&lossacc[1], 1u);
    if (old == 255u) {
      float tot = atomicAdd(&lossacc[0], 0.f);   // atomic read (bypass L1)
      out[0] = tot * (1.f / (float)(B_*S_*L_));
    }
  }
}

extern "C" void kernel_launch(void* const* d_in, const int* in_sizes, int n_in,
                              void* d_out, int out_size, void* d_ws, size_t ws_size,
                              hipStream_t stream) {
  const float* x   = (const float*)d_in[0];
  const float* u   = (const float*)d_in[1];
  const float* Ap  = (const float*)d_in[2];
  const float* W0  = (const float*)d_in[3];
  const float* b0  = (const float*)d_in[4];
  const float* W1  = (const float*)d_in[5];
  const float* b1  = (const float*)d_in[6];
  const float* cw  = (const float*)d_in[7];
  const float* cb  = (const float*)d_in[8];
  const float* Wg  = (const float*)d_in[9];
  const float* bg  = (const float*)d_in[10];
  const float* Wdt = (const float*)d_in[11];
  const float* bdt = (const float*)d_in[12];
  float* out = (float*)d_out;

  // Layout: persistent buffers first; region R of fp32 temps (dead before
  // k_cmfma) is overlaid by ypart (32 slices = 16 MB).
  float* ws    = (float*)d_ws;
  float* zall  = ws;                       // 524288
  float* lossa = zall + 524288;            // 512 (acc, counter)
  bf16_t* oldbf = (bf16_t*)(lossa + 512);  // 294912 f32 slots
  bf16_t* Wgbf  = (bf16_t*)(lossa + 512 + 294912);  // 3548160 f32 slots
  float* R     = lossa + 512 + 294912 + 3548160;
  float* Xp    = R;                        // 131072
  float* Hh    = Xp   + 131072;            // 1048576
  float* Pp    = Hh   + 1048576;           // 524288
  float* dA    = Pp   + 524288;            // 524288
  float* coef  = dA   + 524288;            // 524288
  float* wbuf  = coef + 524288;            // 524288
  float* ypart = R;                        // 32*131072 = 4194304, overlays R

  k_prep<<<CVT_BLOCKS + 512, 256, 0, stream>>>(Wg, Wgbf, x, Xp, lossa);
  k_gemm_tn<1><<<dim3(HID_/64, M_/64), 256, 0, stream>>>(Xp, W0, b0, Hh, M_, HID_, S_);
  k_gemm_tn_s<<<dim3(N_/64, M_/32), 256, 0, stream>>>(Hh, W1, b1, Pp, M_, N_, HID_);
  k_convdelta<<<M_/16, 256, 0, stream>>>(Pp, u, cw, cb, Wg, bg, Wdt, bdt, Ap,
                                         oldbf, dA, coef);
  k_bmfma<<<dim3(64, 16), 256, 0, stream>>>(oldbf, Wgbf, bg, u, coef, wbuf);
  k_scan<<<64, 64, 0, stream>>>(Pp, dA, wbuf, zall);
  k_cmfma<<<dim3(32, 16), 256, 0, stream>>>(oldbf, Wgbf, bg, zall, ypart);
  k_finalize<<<256, 256, 0, stream>>>(ypart, x, out, lossa);
}

// Round 11
// 241.497 us; speedup vs baseline: 1.2641x; 1.0857x over previous
//
#include <hip/hip_runtime.h>
#include <math.h>

#define B_   16
#define L_   128
#define O_   128
#define N_   256
#define S_   64
#define U_   32
#define DEL_ 64
#define HID_ 512
#define CH_  288          // N_+U_
#define M_   2048         // B_*L_
#define KD_  288          // GEMM K for the Wg projections
#define CM_BASE (DEL_ + N_*U_)   // 8256
#define NSLICE 32

typedef __bf16 bf16_t;
typedef bf16_t bf16x8 __attribute__((ext_vector_type(8)));
typedef float  f32x4  __attribute__((ext_vector_type(4)));

#define AS1(p) ((const __attribute__((address_space(1))) void*)(unsigned long long)(const void*)(p))
#define AS3(p) ((__attribute__((address_space(3))) void*)(unsigned int)(unsigned long long)(const void*)(p))

__device__ __forceinline__ float silu_f(float x){ return x / (1.f + expf(-x)); }
__device__ __forceinline__ float softplus_f(float x){
  return fmaxf(x, 0.f) + log1pf(expf(-fabsf(x)));
}

// ---------------- prep: Wg->bf16 convert + pack x + zero loss acc ----------------
#define CVT_BLOCKS 3465   // ceil(887040/256)
__global__ void k_prep(const float* __restrict__ Wg, bf16_t* __restrict__ Wgbf,
                       const float* __restrict__ x, float* __restrict__ Xp,
                       float* __restrict__ lossa){
  if (blockIdx.x == 0 && threadIdx.x < 2) lossa[threadIdx.x] = 0.f;
  if (blockIdx.x < CVT_BLOCKS) {
    int i = blockIdx.x*256 + threadIdx.x;
    if (i >= 887040) return;          // 7096320/8
    float4 a = ((const float4*)Wg)[2*i];
    float4 b = ((const float4*)Wg)[2*i+1];
    bf16x8 o;
    o[0]=(bf16_t)a.x; o[1]=(bf16_t)a.y; o[2]=(bf16_t)a.z; o[3]=(bf16_t)a.w;
    o[4]=(bf16_t)b.x; o[5]=(bf16_t)b.y; o[6]=(bf16_t)b.z; o[7]=(bf16_t)b.w;
    ((bf16x8*)Wgbf)[i] = o;
  } else {
    int i = (blockIdx.x - CVT_BLOCKS)*256 + threadIdx.x;
    if (i >= M_*S_) return;
    int m = i >> 6, c = i & 63;
    int b = m >> 7, t = m & 127;
    Xp[i] = x[((b<<8) + t)*S_ + c];
  }
}

// ---------------- fp32 TN GEMM, 64x64 tile (mlp1) ----------------
#define GEMM_LOAD_TILES(AB, BB, KLD)                                               \
  { _Pragma("unroll")                                                              \
    for (int q = 0; q < 2; q++) {                                                  \
      int idx = tid + q*256; int row = idx >> 3; int c4 = idx & 7;                 \
      float4 av = *(const float4*)((AB) + (size_t)row*(KLD) + kk + c4*4);          \
      float4 bv = *(const float4*)((BB) + (size_t)row*(KLD) + kk + c4*4);          \
      As[c4*4+0][row]=av.x; As[c4*4+1][row]=av.y;                                  \
      As[c4*4+2][row]=av.z; As[c4*4+3][row]=av.w;                                  \
      Bs[c4*4+0][row]=bv.x; Bs[c4*4+1][row]=bv.y;                                  \
      Bs[c4*4+2][row]=bv.z; Bs[c4*4+3][row]=bv.w;                                  \
    } }

#define GEMM_MMA32()                                                               \
  { _Pragma("unroll")                                                              \
    for (int k = 0; k < 32; k++) {                                                 \
      float4 a4 = *(const float4*)&As[k][ty*4];                                    \
      float4 b4 = *(const float4*)&Bs[k][tx*4];                                    \
      float av[4] = {a4.x,a4.y,a4.z,a4.w};                                         \
      float bv[4] = {b4.x,b4.y,b4.z,b4.w};                                         \
      _Pragma("unroll") for (int i=0;i<4;i++)                                      \
        _Pragma("unroll") for (int j=0;j<4;j++)                                    \
          acc[i][j] += av[i]*bv[j];                                                \
    } }

template<int RELU>
__global__ __launch_bounds__(256) void k_gemm_tn(
    const float* __restrict__ A, const float* __restrict__ B,
    const float* __restrict__ bias, float* __restrict__ C,
    int M, int N, int K){
  __shared__ __align__(16) float As[32][68];
  __shared__ __align__(16) float Bs[32][68];
  int tid = threadIdx.x, tx = tid & 15, ty = tid >> 4;
  int nt = blockIdx.x, mt = blockIdx.y;
  const float* Ab = A + (size_t)mt*64*K;
  const float* Bb = B + (size_t)nt*64*K;
  float acc[4][4] = {};
  for (int kk = 0; kk < K; kk += 32) {
    GEMM_LOAD_TILES(Ab, Bb, K);
    __syncthreads();
    GEMM_MMA32();
    __syncthreads();
  }
  #pragma unroll
  for (int i = 0; i < 4; i++) {
    int m = mt*64 + ty*4 + i;
    float4 v; float* vv = (float*)&v;
    #pragma unroll
    for (int j = 0; j < 4; j++) {
      int n = nt*64 + tx*4 + j;
      float t = acc[i][j] + bias[n];
      vv[j] = RELU ? fmaxf(t, 0.f) : t;
    }
    *(float4*)(&C[(size_t)m*N + nt*64 + tx*4]) = v;
  }
}

// ---------------- fp32 TN GEMM, 32x64 tile (mlp2: 256 blocks) ----------------
__global__ __launch_bounds__(256) void k_gemm_tn_s(
    const float* __restrict__ A, const float* __restrict__ B,
    const float* __restrict__ bias, float* __restrict__ C,
    int M, int N, int K){
  __shared__ __align__(16) float As[32][36];
  __shared__ __align__(16) float Bs[32][68];
  int tid = threadIdx.x, tx = tid & 15, ty = tid >> 4;
  int nt = blockIdx.x, mt = blockIdx.y;
  const float* Ab = A + (size_t)mt*32*K;
  const float* Bb = B + (size_t)nt*64*K;
  float acc[2][4] = {};
  for (int kk = 0; kk < K; kk += 32) {
    { int row = tid >> 3, c4 = tid & 7;
      float4 av = *(const float4*)(Ab + (size_t)row*K + kk + c4*4);
      As[c4*4+0][row]=av.x; As[c4*4+1][row]=av.y;
      As[c4*4+2][row]=av.z; As[c4*4+3][row]=av.w; }
    #pragma unroll
    for (int q = 0; q < 2; q++) {
      int idx = tid + q*256; int row = idx >> 3; int c4 = idx & 7;
      float4 bv = *(const float4*)(Bb + (size_t)row*K + kk + c4*4);
      Bs[c4*4+0][row]=bv.x; Bs[c4*4+1][row]=bv.y;
      Bs[c4*4+2][row]=bv.z; Bs[c4*4+3][row]=bv.w; }
    __syncthreads();
    #pragma unroll
    for (int k = 0; k < 32; k++) {
      float a0 = As[k][ty*2], a1 = As[k][ty*2+1];
      float4 b4 = *(const float4*)&Bs[k][tx*4];
      float bv[4] = {b4.x,b4.y,b4.z,b4.w};
      #pragma unroll
      for (int j=0;j<4;j++){ acc[0][j] += a0*bv[j]; acc[1][j] += a1*bv[j]; }
    }
    __syncthreads();
  }
  #pragma unroll
  for (int i = 0; i < 2; i++) {
    int m = mt*32 + ty*2 + i;
    float4 v; float* vv = (float*)&v;
    #pragma unroll
    for (int j = 0; j < 4; j++) vv[j] = acc[i][j] + bias[nt*64 + tx*4 + j];
    *(float4*)(&C[(size_t)m*N + nt*64 + tx*4]) = v;
  }
}

// ---------------- fused conv + delta, 4 rows/block (512 blocks) ----------------
__global__ __launch_bounds__(256) void k_convdelta(
    const float* __restrict__ P, const float* __restrict__ u,
    const float* __restrict__ cw, const float* __restrict__ cb,
    const float* __restrict__ Wg, const float* __restrict__ bg,
    const float* __restrict__ Wdt, const float* __restrict__ bdt,
    const float* __restrict__ Ap, bf16_t* __restrict__ oldbf,
    float* __restrict__ dA, float* __restrict__ coef){
  __shared__ __align__(16) float olds[4*KD_];
  __shared__ float dr[4][64];
  int tid = threadIdx.x;
  int m0 = blockIdx.x * 4;
  int b = m0 >> 7, l0 = m0 & 127;
  // conv phase: 4 rows x 288 ch
  for (int e = tid; e < 4*CH_; e += 256) {
    int r = e / CH_, c = e - r*CH_;
    int l = l0 + r;
    float acc = cb[c];
    #pragma unroll
    for (int k = 0; k < 4; k++) {
      int t = l + k - 1;
      if (t >= 0 && t <= O_-2) {
        float s = (c < N_) ? P[((b<<7)+t)*N_ + c] : u[((b<<8)+t)*U_ + (c-N_)];
        acc += silu_f(s) * cw[c*4 + k];
      }
    }
    float v = silu_f(acc);
    olds[e] = v;
    oldbf[(size_t)(m0+r)*CH_ + c] = (bf16_t)v;
  }
  __syncthreads();
  // draw phase: one (row, d) output per thread, k ascending (bit-stable)
  {
    int d = tid & 63;
    int r = tid >> 6;
    const float* wrow = Wg + (size_t)d*KD_;
    const float* orow = olds + r*KD_;
    float s = 0.f;
    for (int k = 0; k < KD_; k++) s += orow[k] * wrow[k];
    dr[r][d] = s + bg[d];
  }
  __syncthreads();
  // delta phase
  int n = tid;
  float wrow[64];
  #pragma unroll
  for (int d = 0; d < 64; d++) wrow[d] = Wdt[n*64 + d];
  float a0 = Ap[n];
  float a = -(a0 > 0.f ? a0 : expm1f(a0));
  float inva = 1.f / a;
  float bd = bdt[n];
  #pragma unroll
  for (int r = 0; r < 4; r++) {
    float s = bd;
    #pragma unroll
    for (int d = 0; d < 64; d++) s += dr[r][d] * wrow[d];
    float dd = softplus_f(s);
    float e  = expf(dd * a);
    size_t m = m0 + r;
    dA[m*N_ + n]   = e;
    coef[m*N_ + n] = (e - 1.f) * inva;
  }
}

// ================= fragment-order staging, BK=96 (3 col-blocks of 32) =================
#define STAGE_FR96(GBASE, ROW0G, LDSARR)                                                 \
  { _Pragma("unroll")                                                                    \
    for (int c = 0; c < 3; c++) {                                                        \
      _Pragma("unroll")                                                                  \
      for (int q = 0; q < 2; q++) {                                                      \
        int g = wave*2 + q;                                                              \
        const bf16_t* gp = (GBASE) + (size_t)((ROW0G) + g*16 + lm)*KD_ + kk + c*32 + lq*8;\
        __builtin_amdgcn_global_load_lds(AS1(gp), AS3(&(LDSARR)[c*4096 + g*512]), 16, 0, 0);\
      } } }

// ---------------- B-path MFMA (BK=96) ----------------
__global__ __launch_bounds__(256, 2) void k_bmfma(
    const bf16_t* __restrict__ oldbf, const bf16_t* __restrict__ Wgbf,
    const float* __restrict__ bg, const float* __restrict__ u,
    const float* __restrict__ coef, float* __restrict__ wbuf){
  __shared__ __align__(16) bf16_t Asb[3*4096];
  __shared__ __align__(16) bf16_t Bsb[3*4096];
  int tid = threadIdx.x;
  int wave = tid >> 6, lane = tid & 63;
  int wm = wave & 1, wn = wave >> 1;
  int mt = blockIdx.y, nt = blockIdx.x;
  int m0 = mt*128, ncol0 = nt*128;
  int lm = lane & 15, lq = lane >> 4;

  f32x4 acc[4][4];
  #pragma unroll
  for (int i=0;i<4;i++)
    #pragma unroll
    for (int j=0;j<4;j++){ acc[i][j][0]=0.f;acc[i][j][1]=0.f;acc[i][j][2]=0.f;acc[i][j][3]=0.f; }

  for (int kk = 0; kk < KD_; kk += 96) {
    STAGE_FR96(oldbf, m0, Asb);
    STAGE_FR96(Wgbf, DEL_ + ncol0, Bsb);
    __syncthreads();
    for (int c = 0; c < 3; c++) {
      bf16x8 af[4], bff[4];
      #pragma unroll
      for (int i=0;i<4;i++) af[i]  = *(const bf16x8*)&Asb[c*4096 + (wm*4 + i)*512 + lane*8];
      #pragma unroll
      for (int j=0;j<4;j++) bff[j] = *(const bf16x8*)&Bsb[c*4096 + (wn*4 + j)*512 + lane*8];
      #pragma unroll
      for (int i=0;i<4;i++)
        #pragma unroll
        for (int j=0;j<4;j++)
          acc[i][j] = __builtin_amdgcn_mfma_f32_16x16x32_bf16(af[i], bff[j], acc[i][j], 0,0,0);
    }
    __syncthreads();
  }

  float bgv[4];
  #pragma unroll
  for (int j=0;j<4;j++) bgv[j] = bg[DEL_ + ncol0 + wn*64 + j*16 + lm];
  float p[2][4][4];
  #pragma unroll
  for (int a=0;a<2;a++)
    #pragma unroll
    for (int i=0;i<4;i++)
      #pragma unroll
      for (int r=0;r<4;r++) p[a][i][r]=0.f;
  #pragma unroll
  for (int i=0;i<4;i++){
    #pragma unroll
    for (int r=0;r<4;r++){
      int m = m0 + wm*64 + i*16 + lq*4 + r;
      int b = m >> 7, l = m & 127;
      const float* urow = u + ((size_t)(b<<8) + 127 + l)*U_;
      #pragma unroll
      for (int j=0;j<4;j++){
        float uu = urow[(j&1)*16 + lm];
        p[j>>1][i][r] += (acc[i][j][r] + bgv[j]) * uu;
      }
    }
  }
  #pragma unroll
  for (int mk = 1; mk < 16; mk <<= 1){
    #pragma unroll
    for (int a=0;a<2;a++)
      #pragma unroll
      for (int i=0;i<4;i++)
        #pragma unroll
        for (int r=0;r<4;r++) p[a][i][r] += __shfl_xor(p[a][i][r], mk);
  }
  if (lm == 0){
    #pragma unroll
    for (int nl=0;nl<2;nl++){
      int n = ((ncol0 + wn*64 + nl*32) >> 5);
      #pragma unroll
      for (int i=0;i<4;i++)
        #pragma unroll
        for (int r=0;r<4;r++){
          int m = m0 + wm*64 + i*16 + lq*4 + r;
          wbuf[(size_t)m*N_ + n] = coef[(size_t)m*N_ + n] * p[nl][i][r];
        }
    }
  }
}

// ---------------- sequential scan (batched loads) ----------------
__global__ void k_scan(const float* __restrict__ P, const float* __restrict__ dA,
                       const float* __restrict__ w, float* __restrict__ zall){
  int blk = blockIdx.x;             // 64
  int b = blk >> 2;
  int n = (blk & 3)*64 + threadIdx.x;
  float z = P[(size_t)((b<<7) + 127)*N_ + n];
  for (int l0 = 0; l0 < L_; l0 += 16) {
    float da[16], ww[16];
    #pragma unroll
    for (int t = 0; t < 16; t++) {
      size_t idx = (size_t)((b<<7) + l0 + t)*N_ + n;
      da[t] = dA[idx]; ww[t] = w[idx];
    }
    #pragma unroll
    for (int t = 0; t < 16; t++) {
      size_t idx = (size_t)((b<<7) + l0 + t)*N_ + n;
      z = z * da[t] + ww[t];
      zall[idx] = z;
    }
  }
}

// ---------------- C-path MFMA (BK=96): 4 n-tiles/block, per-block y slice ----------------
__global__ __launch_bounds__(256, 2) void k_cmfma(
    const bf16_t* __restrict__ oldbf, const bf16_t* __restrict__ Wgbf,
    const float* __restrict__ bg, const float* __restrict__ zall,
    float* __restrict__ ypart){
  __shared__ union {
    struct { bf16_t A[3*4096]; bf16_t B[3*4096]; } st;   // 48 KB staging
    float ylds[128][64];                                  // 32 KB (after staging dead)
  } sm;
  int tid = threadIdx.x;
  int wave = tid >> 6, lane = tid & 63;
  int wm = wave & 1, wn = wave >> 1;
  int mt = blockIdx.y, grp = blockIdx.x;   // 32 groups of 4 n-tiles
  int m0 = mt*128;
  int lm = lane & 15, lq = lane >> 4;

  f32x4 yacc[4][4];
  #pragma unroll
  for (int i=0;i<4;i++)
    #pragma unroll
    for (int j=0;j<4;j++){ yacc[i][j][0]=0.f;yacc[i][j][1]=0.f;yacc[i][j][2]=0.f;yacc[i][j][3]=0.f; }

  for (int it = 0; it < 4; it++) {
    int ncol0 = (grp*4 + it)*128;
    f32x4 acc[4][4];
    #pragma unroll
    for (int i=0;i<4;i++)
      #pragma unroll
      for (int j=0;j<4;j++){ acc[i][j][0]=0.f;acc[i][j][1]=0.f;acc[i][j][2]=0.f;acc[i][j][3]=0.f; }

    for (int kk = 0; kk < KD_; kk += 96) {
      STAGE_FR96(oldbf, m0, sm.st.A);
      STAGE_FR96(Wgbf, CM_BASE + ncol0, sm.st.B);
      __syncthreads();
      for (int c = 0; c < 3; c++) {
        bf16x8 af[4], bff[4];
        #pragma unroll
        for (int i=0;i<4;i++) af[i]  = *(const bf16x8*)&sm.st.A[c*4096 + (wm*4 + i)*512 + lane*8];
        #pragma unroll
        for (int j=0;j<4;j++) bff[j] = *(const bf16x8*)&sm.st.B[c*4096 + (wn*4 + j)*512 + lane*8];
        #pragma unroll
        for (int i=0;i<4;i++)
          #pragma unroll
          for (int j=0;j<4;j++)
            acc[i][j] = __builtin_amdgcn_mfma_f32_16x16x32_bf16(af[i], bff[j], acc[i][j], 0,0,0);
      }
      __syncthreads();
    }

    int n = (ncol0 >> 6) + wn;
    float bgv[4];
    #pragma unroll
    for (int j=0;j<4;j++) bgv[j] = bg[CM_BASE + ncol0 + wn*64 + j*16 + lm];
    #pragma unroll
    for (int i=0;i<4;i++){
      #pragma unroll
      for (int r=0;r<4;r++){
        int m = m0 + wm*64 + i*16 + lq*4 + r;
        float zv = zall[(size_t)m*N_ + n];
        #pragma unroll
        for (int j=0;j<4;j++)
          yacc[i][j][r] += (acc[i][j][r] + bgv[j]) * zv;
      }
    }
  }

  __syncthreads();
  if (wn == 1){
    #pragma unroll
    for (int i=0;i<4;i++)
      #pragma unroll
      for (int j=0;j<4;j++)
        #pragma unroll
        for (int r=0;r<4;r++){
          int ml = wm*64 + i*16 + lq*4 + r;
          sm.ylds[ml][j*16 + lm] = yacc[i][j][r];
        }
  }
  __syncthreads();
  if (wn == 0){
    float* dst = ypart + (size_t)grp*(M_*S_);
    #pragma unroll
    for (int i=0;i<4;i++)
      #pragma unroll
      for (int j=0;j<4;j++)
        #pragma unroll
        for (int r=0;r<4;r++){
          int ml = wm*64 + i*16 + lq*4 + r;
          int s = j*16 + lm;
          dst[(size_t)(m0+ml)*S_ + s] = yacc[i][j][r] + sm.ylds[ml][s];
        }
  }
}

// ---------------- finalize: sum slices, write ys (L,B,S), fused loss ----------------
__global__ void k_finalize(const float* __restrict__ ypart, const float* __restrict__ x,
                           float* __restrict__ out, float* __restrict__ lossacc){
  __shared__ float red[256];
  int tid = threadIdx.x;
  float ls = 0.f;
  #pragma unroll
  for (int q = 0; q < 2; q++) {
    int e = blockIdx.x*512 + q*256 + tid;
    int m = e >> 6, s = e & 63;
    int b = m >> 7, l = m & 127;
    float yv = 0.f;
    #pragma unroll 8
    for (int g = 0; g < NSLICE; g++) yv += ypart[(size_t)g*(M_*S_) + e];
    out[1 + (size_t)((l<<4) + b)*S_ + s] = yv;
    float xv = x[((size_t)(b<<8) + 128 + l)*S_ + s];
    float d = yv - xv;
    ls += d*d;
  }
  red[tid] = ls; __syncthreads();
  for (int st = 128; st > 0; st >>= 1) {
    if (tid < st) red[tid] += red[tid+st];
    __syncthreads();
  }
  if (tid == 0) {
    atomicAdd(&lossacc[0], red[0]);
    __threadfence();
    unsigned old = atomicAdd((unsigned*)&lossacc[1], 1u);
    if (old == 255u) {
      float tot = atomicAdd(&lossacc[0], 0.f);   // atomic read (bypass L1)
      out[0] = tot * (1.f / (float)(B_*S_*L_));
    }
  }
}

extern "C" void kernel_launch(void* const* d_in, const int* in_sizes, int n_in,
                              void* d_out, int out_size, void* d_ws, size_t ws_size,
                              hipStream_t stream) {
  const float* x   = (const float*)d_in[0];
  const float* u   = (const float*)d_in[1];
  const float* Ap  = (const float*)d_in[2];
  const float* W0  = (const float*)d_in[3];
  const float* b0  = (const float*)d_in[4];
  const float* W1  = (const float*)d_in[5];
  const float* b1  = (const float*)d_in[6];
  const float* cw  = (const float*)d_in[7];
  const float* cb  = (const float*)d_in[8];
  const float* Wg  = (const float*)d_in[9];
  const float* bg  = (const float*)d_in[10];
  const float* Wdt = (const float*)d_in[11];
  const float* bdt = (const float*)d_in[12];
  float* out = (float*)d_out;

  // Layout: persistent buffers first; region R of fp32 temps (dead before
  // k_cmfma) is overlaid by ypart (32 slices = 16 MB).
  float* ws    = (float*)d_ws;
  float* zall  = ws;                       // 524288
  float* lossa = zall + 524288;            // 512 (acc, counter)
  bf16_t* oldbf = (bf16_t*)(lossa + 512);  // 294912 f32 slots
  bf16_t* Wgbf  = (bf16_t*)(lossa + 512 + 294912);  // 3548160 f32 slots
  float* R     = lossa + 512 + 294912 + 3548160;
  float* Xp    = R;                        // 131072
  float* Hh    = Xp   + 131072;            // 1048576
  float* Pp    = Hh   + 1048576;           // 524288
  float* dA    = Pp   + 524288;            // 524288
  float* coef  = dA   + 524288;            // 524288
  float* wbuf  = coef + 524288;            // 524288
  float* ypart = R;                        // 32*131072 = 4194304, overlays R

  k_prep<<<CVT_BLOCKS + 512, 256, 0, stream>>>(Wg, Wgbf, x, Xp, lossa);
  k_gemm_tn<1><<<dim3(HID_/64, M_/64), 256, 0, stream>>>(Xp, W0, b0, Hh, M_, HID_, S_);
  k_gemm_tn_s<<<dim3(N_/64, M_/32), 256, 0, stream>>>(Hh, W1, b1, Pp, M_, N_, HID_);
  k_convdelta<<<M_/4, 256, 0, stream>>>(Pp, u, cw, cb, Wg, bg, Wdt, bdt, Ap,
                                        oldbf, dA, coef);
  k_bmfma<<<dim3(64, 16), 256, 0, stream>>>(oldbf, Wgbf, bg, u, coef, wbuf);
  k_scan<<<64, 64, 0, stream>>>(Pp, dA, wbuf, zall);
  k_cmfma<<<dim3(32, 16), 256, 0, stream>>>(oldbf, Wgbf, bg, zall, ypart);
  k_finalize<<<256, 256, 0, stream>>>(ypart, x, out, lossa);
}